// Round 1
// baseline (3160.434 us; speedup 1.0000x reference)
//
#include <hip/hip_runtime.h>
#include <hip/hip_bf16.h>

#define BB 4
#define SS 4096
#define DD 512
#define LWW 512
#define CC 64
#define NCH 64

typedef unsigned short u16;
using fragAB = __attribute__((ext_vector_type(8))) short;
using fragC  = __attribute__((ext_vector_type(4))) float;

__device__ __forceinline__ short f2bf(float f){
  unsigned u = __float_as_uint(f);
  u = (u + 0x7FFFu + ((u >> 16) & 1u)) >> 16;
  return (short)u;
}
__device__ __forceinline__ float bf2f(short s){
  return __uint_as_float(((unsigned)(u16)s) << 16);
}
__device__ __forceinline__ fragC zeroC(){ fragC z = {0.f,0.f,0.f,0.f}; return z; }

// fragment from row-major fp32 matrix: element [r0 + lane%16][k0 + 8*(lane/16) + i]
__device__ __forceinline__ fragAB frag_f32(const float* __restrict__ base, int ld, int r0, int k0, int lane){
  const float* p = base + (size_t)(r0 + (lane & 15)) * ld + k0 + ((lane >> 4) << 3);
  fragAB f;
#pragma unroll
  for (int i = 0; i < 8; ++i) f[i] = f2bf(p[i]);
  return f;
}
__device__ __forceinline__ fragAB frag_bf16g(const u16* __restrict__ base, int ld, int r0, int k0, int lane){
  return *(const fragAB*)(base + (size_t)(r0 + (lane & 15)) * ld + k0 + ((lane >> 4) << 3));
}
__device__ __forceinline__ fragAB frag_lds(const short* base, int ld, int r0, int k0, int lane){
  return *(const fragAB*)(base + (r0 + (lane & 15)) * ld + k0 + ((lane >> 4) << 3));
}
#define MFMA16(a,b,c) __builtin_amdgcn_mfma_f32_16x16x32_bf16(a,b,c,0,0,0)

// ---------------- init state ----------------
__global__ void k_init(const float* __restrict__ iw1, const float* __restrict__ ib1,
                       const float* __restrict__ iw2, const float* __restrict__ ib2,
                       float* __restrict__ w1, float* __restrict__ mw1,
                       float* __restrict__ w2b, float* __restrict__ mw2,
                       float* __restrict__ b1, float* __restrict__ mb1,
                       float* __restrict__ b2, float* __restrict__ mb2){
  int i = blockIdx.x * 256 + threadIdx.x;
  if (i < LWW * DD){
    float a = iw1[i], c = iw2[i];
#pragma unroll
    for (int b = 0; b < BB; ++b){
      w1 [(size_t)b*LWW*DD + i] = a;  mw1[(size_t)b*LWW*DD + i] = 0.f;
      w2b[(size_t)b*DD*LWW + i] = c;  mw2[(size_t)b*DD*LWW + i] = 0.f;
    }
  }
  if (i < LWW){
    float v1 = ib1[i], v2 = ib2[i];
#pragma unroll
    for (int b = 0; b < BB; ++b){
      b1[b*LWW+i] = v1; mb1[b*LWW+i] = 0.f;
      b2[b*DD +i] = v2; mb2[b*DD +i] = 0.f;
    }
  }
}

// ---------------- Q,K,V projections (raw) ----------------
__global__ __launch_bounds__(256) void k_proj(const float* __restrict__ x,
    const float* __restrict__ Wq, const float* __restrict__ Wk, const float* __restrict__ Wv,
    u16* __restrict__ Qb, u16* __restrict__ Kb, float* __restrict__ V){
  int mt = blockIdx.x / 12, nt = blockIdx.x % 12;
  int lane = threadIdx.x & 63, wid = threadIdx.x >> 6;
  const float* W = (nt < 4) ? Wq : (nt < 8) ? Wk : Wv;
  int n0 = (nt & 3) * 128;
  int m0 = mt * 64 + wid * 16;
  fragC acc[8];
#pragma unroll
  for (int i = 0; i < 8; ++i) acc[i] = zeroC();
  for (int k0 = 0; k0 < DD; k0 += 32){
    fragAB a = frag_f32(x, DD, m0, k0, lane);
#pragma unroll
    for (int nf = 0; nf < 8; ++nf){
      fragAB bfr = frag_f32(W, DD, n0 + nf*16, k0, lane);
      acc[nf] = MFMA16(a, bfr, acc[nf]);
    }
  }
#pragma unroll
  for (int nf = 0; nf < 8; ++nf){
#pragma unroll
    for (int r = 0; r < 4; ++r){
      int m = m0 + ((lane >> 4) << 2) + r;
      int col = n0 + nf*16 + (lane & 15);
      float v = acc[nf][r];
      size_t idx = (size_t)m * DD + col;
      if (nt < 4)      Qb[idx] = (u16)f2bf(v);
      else if (nt < 8) Kb[idx] = (u16)f2bf(v);
      else             V [idx] = v;
    }
  }
}

// ---------------- l2-normalize Q,K rows in place ----------------
__global__ __launch_bounds__(256) void k_norm(u16* __restrict__ Qb, u16* __restrict__ Kb){
  int idx = blockIdx.x * 4 + (threadIdx.x >> 6);
  int lane = threadIdx.x & 63;
  u16* p = (idx < BB*SS ? Qb + (size_t)idx * DD
                        : Kb + (size_t)(idx - BB*SS) * DD) + lane * 8;
  fragAB v = *(const fragAB*)p;
  float f[8]; float s = 0.f;
#pragma unroll
  for (int i = 0; i < 8; ++i){ f[i] = bf2f(v[i]); s += f[i]*f[i]; }
#pragma unroll
  for (int o = 32; o > 0; o >>= 1) s += __shfl_xor(s, o, 64);
  float inv = 1.f / fmaxf(sqrtf(s), 1e-12f);
  fragAB o8;
#pragma unroll
  for (int i = 0; i < 8; ++i) o8[i] = f2bf(f[i] * inv);
  *(fragAB*)p = o8;
}

// ---------------- gates a,e,theta per (batch, chunk) ----------------
__global__ __launch_bounds__(256) void k_gates(const float* __restrict__ x,
    const float* __restrict__ aw, const float* __restrict__ ab,
    const float* __restrict__ ew, const float* __restrict__ eb,
    const float* __restrict__ tw, const float* __restrict__ tb,
    float* __restrict__ aet){
  __shared__ float part[64][4][3];
  __shared__ float rowsig[64][3];
  int b = blockIdx.x >> 6, t = blockIdx.x & 63;
  int tid = threadIdx.x;
  int r = tid >> 2, p = tid & 3;
  const float* xp = x + ((size_t)b*SS + (size_t)t*CC + r) * DD + p * 128;
  float s0 = 0.f, s1 = 0.f, s2 = 0.f;
  for (int i = 0; i < 128; ++i){
    float xv = xp[i];
    s0 += xv * aw[p*128+i]; s1 += xv * ew[p*128+i]; s2 += xv * tw[p*128+i];
  }
  part[r][p][0] = s0; part[r][p][1] = s1; part[r][p][2] = s2;
  __syncthreads();
  if (tid < 64){
    float a_ = part[tid][0][0]+part[tid][1][0]+part[tid][2][0]+part[tid][3][0] + ab[0];
    float e_ = part[tid][0][1]+part[tid][1][1]+part[tid][2][1]+part[tid][3][1] + eb[0];
    float t_ = part[tid][0][2]+part[tid][1][2]+part[tid][2][2]+part[tid][3][2] + tb[0];
    rowsig[tid][0] = 1.f/(1.f+expf(-a_));
    rowsig[tid][1] = 1.f/(1.f+expf(-e_));
    rowsig[tid][2] = 1.f/(1.f+expf(-t_));
  }
  __syncthreads();
  if (tid < 3){
    float s = 0.f;
    for (int i = 0; i < 64; ++i) s += rowsig[i][tid];
    aet[((size_t)b*NCH + t)*3 + tid] = s * (1.f/64.f);
  }
}

// ---------------- Stage A (h-partitioned): dh, g_w1, w1/b1 update, pre/hq for chunk t ----------------
__global__ __launch_bounds__(256) void k_stageA(
    const u16* __restrict__ Qb, const u16* __restrict__ Kb,
    const float* __restrict__ dvp, float* __restrict__ actd,
    const float* __restrict__ aet,
    float* __restrict__ w1, float* __restrict__ mw1,
    float* __restrict__ b1, float* __restrict__ mb1,
    const float* __restrict__ w2old,
    u16* __restrict__ hkb, u16* __restrict__ hqs, int t)
{
  __shared__ __align__(16) short s_big[512*72];   // union: w2T[32][520] / KcT[512][72] / w1tile[32][520]
  __shared__ __align__(16) short s_dhT[32*72];
  __shared__ float s_b1[32];
  int b  = blockIdx.x >> 4;
  int h0 = (blockIdx.x & 15) * 32;
  int tid = threadIdx.x, lane = tid & 63, wid = tid >> 6;
  const size_t WOFF = (size_t)b * LWW * DD;

  if (t > 0){
    { // stage w2T tile: s_big[h][d] = w2old[b][d][h0+h], ld 520
      int h = tid & 31, db = tid >> 5;
      for (int j = 0; j < 64; ++j){
        int d = db + j*8;
        s_big[h*520 + d] = f2bf(w2old[WOFF + (size_t)d*LWW + h0 + h]);
      }
    }
    __syncthreads();
    { // dh[c][hl] = (dvp @ w2T) * actder
      int m0 = wid * 16;
      fragC a0 = zeroC(), a1 = zeroC();
      const float* dv = dvp + (size_t)b*CC*DD;
      for (int k0 = 0; k0 < DD; k0 += 32){
        fragAB af = frag_f32(dv, DD, m0, k0, lane);
        a0 = MFMA16(af, frag_lds(s_big, 520, 0,  k0, lane), a0);
        a1 = MFMA16(af, frag_lds(s_big, 520, 16, k0, lane), a1);
      }
#pragma unroll
      for (int nf = 0; nf < 2; ++nf){
        fragC av = nf ? a1 : a0;
#pragma unroll
        for (int r = 0; r < 4; ++r){
          int c  = m0 + ((lane >> 4) << 2) + r;
          int hl = nf*16 + (lane & 15);
          float v = av[r] * actd[((size_t)b*CC + c)*LWW + h0 + hl];
          s_dhT[hl*72 + c] = f2bf(v);
        }
      }
    }
    __syncthreads();
    { // stage KcT (chunk t-1): s_big[d][c] ld 72
      const u16* Kc = Kb + ((size_t)b*SS + (size_t)(t-1)*CC) * DD;
      int c = tid >> 2, d8 = (tid & 3) * 8;
      for (int j = 0; j < 16; ++j){
        int d = d8 + j*32;
        fragAB kv = *(const fragAB*)(Kc + (size_t)c*DD + d);
#pragma unroll
        for (int i = 0; i < 8; ++i) s_big[(d+i)*72 + c] = kv[i];
      }
    }
    __syncthreads();
    { // g_w1 [h=32][d=512], K=64 ; then updates
      int n0w = wid * 128;
      fragC accg[2][8];
#pragma unroll
      for (int i = 0; i < 2; ++i)
#pragma unroll
        for (int j = 0; j < 8; ++j) accg[i][j] = zeroC();
#pragma unroll
      for (int kk = 0; kk < 2; ++kk){
        int k0 = kk * 32;
        fragAB a0 = frag_lds(s_dhT, 72, 0,  k0, lane);
        fragAB a1 = frag_lds(s_dhT, 72, 16, k0, lane);
#pragma unroll
        for (int nf = 0; nf < 8; ++nf){
          fragAB bf = frag_lds(s_big, 72, n0w + nf*16, k0, lane);
          accg[0][nf] = MFMA16(a0, bf, accg[0][nf]);
          accg[1][nf] = MFMA16(a1, bf, accg[1][nf]);
        }
      }
      __syncthreads();   // KcT reads done; s_big reused as w1tile below
      const float* g3 = aet + ((size_t)b*NCH + (t-1)) * 3;
      float ga = g3[0], ge = g3[1], gth = g3[2];
#pragma unroll
      for (int mf = 0; mf < 2; ++mf)
#pragma unroll
        for (int nf = 0; nf < 8; ++nf)
#pragma unroll
          for (int r = 0; r < 4; ++r){
            int h = h0 + mf*16 + ((lane >> 4) << 2) + r;
            int d = n0w + nf*16 + (lane & 15);
            size_t idx = WOFF + (size_t)h*DD + d;
            float g  = accg[mf][nf][r] * (1.f/64.f);
            float m_ = ge*mw1[idx] - gth*g;
            float w_ = (1.f-ga)*w1[idx] + m_;
            mw1[idx] = m_; w1[idx] = w_;
            s_big[(h-h0)*520 + d] = f2bf(w_);
          }
      if (tid < 32){
        int h = h0 + tid;
        float s = 0.f;
        for (int c = 0; c < CC; ++c) s += bf2f(s_dhT[tid*72 + c]);
        float gb = s * (1.f/64.f);
        float m_ = ge*mb1[b*LWW+h] - gth*gb;
        float bn = (1.f-ga)*b1[b*LWW+h] + m_;
        mb1[b*LWW+h] = m_; b1[b*LWW+h] = bn;
        s_b1[tid] = bn;
      }
    }
  } else {
    // t == 0: load initial w1 tile + b1 into LDS
    int hl = tid >> 3, d0 = (tid & 7) * 64;
    for (int i = 0; i < 64; ++i){
      int d = d0 + i;
      s_big[hl*520 + d] = f2bf(w1[WOFF + (size_t)(h0+hl)*DD + d]);
    }
    if (tid < 32) s_b1[tid] = b1[b*LWW + h0 + tid];
  }
  __syncthreads();
  { // pre & hq for chunk t; activations; store hk/actder/hq_silu
    const u16* Kc = Kb + ((size_t)b*SS + (size_t)t*CC) * DD;
    const u16* Qc = Qb + ((size_t)b*SS + (size_t)t*CC) * DD;
    int m0 = wid * 16;
    fragC ap0 = zeroC(), ap1 = zeroC(), aq0 = zeroC(), aq1 = zeroC();
    for (int k0 = 0; k0 < DD; k0 += 32){
      fragAB ak  = frag_bf16g(Kc, DD, m0, k0, lane);
      fragAB aqf = frag_bf16g(Qc, DD, m0, k0, lane);
      fragAB b0  = frag_lds(s_big, 520, 0,  k0, lane);
      fragAB b1f = frag_lds(s_big, 520, 16, k0, lane);
      ap0 = MFMA16(ak,  b0,  ap0); ap1 = MFMA16(ak,  b1f, ap1);
      aq0 = MFMA16(aqf, b0,  aq0); aq1 = MFMA16(aqf, b1f, aq1);
    }
#pragma unroll
    for (int nf = 0; nf < 2; ++nf){
      fragC pv = nf ? ap1 : ap0;
      fragC qv = nf ? aq1 : aq0;
#pragma unroll
      for (int r = 0; r < 4; ++r){
        int c  = m0 + ((lane >> 4) << 2) + r;
        int hl = nf*16 + (lane & 15);
        float bb = s_b1[hl];
        float pre = pv[r] + bb;
        float sg  = 1.f/(1.f+expf(-pre));
        float hkv = pre * sg;
        float ad  = sg * (1.f + pre * (1.f - sg));
        size_t oi = ((size_t)b*CC + c)*LWW + h0 + hl;
        hkb[oi]  = (u16)f2bf(hkv);
        actd[oi] = ad;
        float hqv = qv[r] + bb;
        float s2  = 1.f/(1.f+expf(-hqv));
        hqs[oi] = (u16)f2bf(hqv * s2);
      }
    }
  }
}

// ---------------- Stage B (d-partitioned): y, vp, dvp, g_w2, w2/b2 update ----------------
__global__ __launch_bounds__(256) void k_stageB(
    const u16* __restrict__ hkb, const u16* __restrict__ hqs,
    const float* __restrict__ V, const float* __restrict__ aet,
    const float* __restrict__ w2old, float* __restrict__ w2new,
    float* __restrict__ mw2, float* __restrict__ b2, float* __restrict__ mb2,
    float* __restrict__ dvp, float* __restrict__ out, int t)
{
  __shared__ __align__(16) short s_hkT[512*72];
  __shared__ __align__(16) short s_dvT[32*72];
  int b  = blockIdx.x >> 4;
  int d0 = (blockIdx.x & 15) * 32;
  int tid = threadIdx.x, lane = tid & 63, wid = tid >> 6;
  const size_t WOFF = (size_t)b * DD * LWW;
  const u16* hkp = hkb + (size_t)b*CC*LWW;
  const u16* hqp = hqs + (size_t)b*CC*LWW;
  { // y, vp, dvp
    int m0 = wid * 16;
    fragC y0 = zeroC(), y1 = zeroC(), v0 = zeroC(), v1 = zeroC();
    for (int k0 = 0; k0 < LWW; k0 += 32){
      fragAB aq = frag_bf16g(hqp, LWW, m0, k0, lane);
      fragAB ak = frag_bf16g(hkp, LWW, m0, k0, lane);
      fragAB b0  = frag_f32(w2old + WOFF, LWW, d0,      k0, lane);
      fragAB b1f = frag_f32(w2old + WOFF, LWW, d0 + 16, k0, lane);
      y0 = MFMA16(aq, b0, y0); y1 = MFMA16(aq, b1f, y1);
      v0 = MFMA16(ak, b0, v0); v1 = MFMA16(ak, b1f, v1);
    }
#pragma unroll
    for (int nf = 0; nf < 2; ++nf){
      fragC yv = nf ? y1 : y0, vv = nf ? v1 : v0;
#pragma unroll
      for (int r = 0; r < 4; ++r){
        int c = m0 + ((lane >> 4) << 2) + r;
        int d = d0 + nf*16 + (lane & 15);
        float bb = b2[b*DD + d];
        size_t oi = ((size_t)b*SS + (size_t)t*CC + c) * DD + d;
        out[oi] = yv[r] + bb;
        float dvv = (vv[r] + bb - V[oi]) * (2.f/512.f);
        dvp[((size_t)b*CC + c)*DD + d] = dvv;
        s_dvT[(d-d0)*72 + c] = f2bf(dvv);
      }
    }
  }
  __syncthreads();
  { // stage hkT: s_hkT[h][c], ld 72
    int c = tid >> 2, h8 = (tid & 3) * 8;
    for (int j = 0; j < 16; ++j){
      int h = h8 + j*32;
      fragAB hv = *(const fragAB*)(hkp + (size_t)c*LWW + h);
#pragma unroll
      for (int i = 0; i < 8; ++i) s_hkT[(h+i)*72 + c] = hv[i];
    }
  }
  __syncthreads();
  { // g_w2 [d=32][h=512], K=64 ; then updates
    int n0w = wid * 128;
    fragC accg[2][8];
#pragma unroll
    for (int i = 0; i < 2; ++i)
#pragma unroll
      for (int j = 0; j < 8; ++j) accg[i][j] = zeroC();
#pragma unroll
    for (int kk = 0; kk < 2; ++kk){
      int k0 = kk * 32;
      fragAB a0 = frag_lds(s_dvT, 72, 0,  k0, lane);
      fragAB a1 = frag_lds(s_dvT, 72, 16, k0, lane);
#pragma unroll
      for (int nf = 0; nf < 8; ++nf){
        fragAB bf = frag_lds(s_hkT, 72, n0w + nf*16, k0, lane);
        accg[0][nf] = MFMA16(a0, bf, accg[0][nf]);
        accg[1][nf] = MFMA16(a1, bf, accg[1][nf]);
      }
    }
    const float* g3 = aet + ((size_t)b*NCH + t) * 3;
    float ga = g3[0], ge = g3[1], gth = g3[2];
#pragma unroll
    for (int mf = 0; mf < 2; ++mf)
#pragma unroll
      for (int nf = 0; nf < 8; ++nf)
#pragma unroll
        for (int r = 0; r < 4; ++r){
          int d = d0 + mf*16 + ((lane >> 4) << 2) + r;
          int h = n0w + nf*16 + (lane & 15);
          size_t idx = WOFF + (size_t)d*LWW + h;
          float g  = accg[mf][nf][r] * (1.f/64.f);
          float m_ = ge*mw2[idx] - gth*g;
          float w_ = (1.f-ga)*w2old[idx] + m_;
          mw2[idx] = m_; w2new[idx] = w_;
        }
    if (tid < 32){
      int d = d0 + tid;
      float s = 0.f;
      for (int c2 = 0; c2 < CC; ++c2) s += bf2f(s_dvT[tid*72 + c2]);
      float gb = s * (1.f/64.f);
      float m_ = ge*mb2[b*DD+d] - gth*gb;
      float bn = (1.f-ga)*b2[b*DD+d] + m_;
      mb2[b*DD+d] = m_; b2[b*DD+d] = bn;
    }
  }
}

extern "C" void kernel_launch(void* const* d_in, const int* in_sizes, int n_in,
                              void* d_out, int out_size, void* d_ws, size_t ws_size,
                              hipStream_t stream){
  const float* x   = (const float*)d_in[0];
  const float* Wq  = (const float*)d_in[1];
  const float* Wk  = (const float*)d_in[2];
  const float* Wv  = (const float*)d_in[3];
  const float* iw1 = (const float*)d_in[4];
  const float* ib1 = (const float*)d_in[5];
  const float* iw2 = (const float*)d_in[6];
  const float* ib2 = (const float*)d_in[7];
  const float* aw  = (const float*)d_in[8];
  const float* ab  = (const float*)d_in[9];
  const float* ew  = (const float*)d_in[10];
  const float* eb  = (const float*)d_in[11];
  const float* tw  = (const float*)d_in[12];
  const float* tb  = (const float*)d_in[13];
  float* out = (float*)d_out;

  float* fw = (float*)d_ws;
  float* V    = fw;  fw += (size_t)BB*SS*DD;
  float* w1   = fw;  fw += (size_t)BB*LWW*DD;
  float* mw1  = fw;  fw += (size_t)BB*LWW*DD;
  float* w2b  = fw;  fw += (size_t)2*BB*DD*LWW;
  float* mw2  = fw;  fw += (size_t)BB*DD*LWW;
  float* b1   = fw;  fw += BB*LWW;
  float* mb1  = fw;  fw += BB*LWW;
  float* b2   = fw;  fw += BB*DD;
  float* mb2  = fw;  fw += BB*DD;
  float* dvp  = fw;  fw += (size_t)BB*CC*DD;
  float* actd = fw;  fw += (size_t)BB*CC*LWW;
  float* aet  = fw;  fw += (size_t)BB*NCH*3;
  u16* Qb  = (u16*)fw;
  u16* Kb  = Qb  + (size_t)BB*SS*DD;
  u16* hkb = Kb  + (size_t)BB*SS*DD;
  u16* hqs = hkb + (size_t)BB*CC*LWW;

  k_init <<<1024, 256, 0, stream>>>(iw1, ib1, iw2, ib2, w1, mw1, w2b, mw2, b1, mb1, b2, mb2);
  k_proj <<<3072, 256, 0, stream>>>(x, Wq, Wk, Wv, Qb, Kb, V);
  k_norm <<<8192, 256, 0, stream>>>(Qb, Kb);
  k_gates<<<256,  256, 0, stream>>>(x, aw, ab, ew, eb, tw, tb, aet);

  const size_t WBUF = (size_t)BB*DD*LWW;
  for (int t = 0; t < NCH; ++t){
    const float* w2A = w2b + ((size_t)((t+1)&1))*WBUF;   // buffer used by chunk t-1 forward (unused at t=0)
    k_stageA<<<64, 256, 0, stream>>>(Qb, Kb, dvp, actd, aet, w1, mw1, b1, mb1, w2A, hkb, hqs, t);
    const float* w2o = w2b + ((size_t)(t&1))*WBUF;
    float*       w2n = w2b + ((size_t)((t+1)&1))*WBUF;
    k_stageB<<<64, 256, 0, stream>>>(hkb, hqs, V, aet, w2o, w2n, mw2, b2, mb2, dvp, out, t);
  }
}